// Round 1
// baseline (1139.633 us; speedup 1.0000x reference)
//
#include <hip/hip_runtime.h>

#define HH 96
#define WW 96
#define CC 21
#define BB 2
#define NN (HH*WW)          // 9216
#define ZS 6                // j-splits across blockIdx.z for load balance
#define JSEG (NN/ZS)        // 1536
#define GSEG (JSEG/4)       // 384 j's per 64-thread group
#define NTILE (NN/64)       // 144 i-tiles

// Pre-scale features by sqrt(0.5)/theta so K = exp(-sum(d^2)) directly.
__device__ __constant__ float kSA = 0.70710678118f / 160.0f;  // spatial (bilateral)
__device__ __constant__ float kSB = 0.70710678118f / 3.0f;    // color
#define GINV (1.0f/18.0f)   // spatial kernel: exp(-d^2/18)

// ---------------- softmax over C + pack bilateral features -----------------
// q layout [B][N][C] (same as unary input & output). Writes:
//   sm_cn [B][C][N]  (for separable spatial conv)
//   pm    [B][N][32] (packed row per pixel: sm[0..20], r,g,b scaled, y,x scaled)
__global__ __launch_bounds__(256) void softmax_pack_kernel(
    const float* __restrict__ q, const float* __restrict__ rgb,
    float* __restrict__ sm_cn, float* __restrict__ pm)
{
    int idx = blockIdx.x * 256 + threadIdx.x;
    if (idx >= BB * NN) return;
    int b = idx / NN, i = idx - b * NN;
    const float* qp = q + (size_t)idx * CC;
    float v[CC];
    float m = -1e30f;
#pragma unroll
    for (int c = 0; c < CC; c++) { v[c] = qp[c]; m = fmaxf(m, v[c]); }
    float s = 0.f;
#pragma unroll
    for (int c = 0; c < CC; c++) { v[c] = __expf(v[c] - m); s += v[c]; }
    float inv = 1.0f / s;
    float* pp = pm + (size_t)idx * 32;
    float* smb = sm_cn + (size_t)b * CC * NN + i;
#pragma unroll
    for (int c = 0; c < CC; c++) {
        float sv = v[c] * inv;
        smb[(size_t)c * NN] = sv;
        pp[c] = sv;
    }
    const float* rp = rgb + (size_t)idx * 3;
    pp[21] = rp[0] * kSB; pp[22] = rp[1] * kSB; pp[23] = rp[2] * kSB;
    int y = i / WW, x = i - y * WW;
    pp[24] = (float)y * kSA; pp[25] = (float)x * kSA;
    pp[26] = 0.f; pp[27] = 0.f; pp[28] = 0.f; pp[29] = 0.f; pp[30] = 0.f; pp[31] = 0.f;
}

// ---------------- separable spatial Gaussian, pass 1 (along x) -------------
__global__ __launch_bounds__(256) void spatial_x_kernel(
    const float* __restrict__ src, float* __restrict__ dst)
{
    int idx = blockIdx.x * 256 + threadIdx.x;
    if (idx >= BB * CC * NN) return;
    int x1 = idx % WW;
    int rowbase = idx - x1;
    float acc = 0.f;
    for (int x = 0; x < WW; x++) {
        int d = x1 - x;
        acc = fmaf(__expf(-(float)(d * d) * GINV), src[rowbase + x], acc);
    }
    dst[idx] = acc;
}

// ---------------- pass 2 (along y) + analytic normalization ----------------
__global__ __launch_bounds__(256) void spatial_y_kernel(
    const float* __restrict__ src, float* __restrict__ dst)
{
    int idx = blockIdx.x * 256 + threadIdx.x;
    if (idx >= BB * CC * NN) return;
    int x1 = idx % WW;
    int y1 = (idx / WW) % HH;
    int colbase = idx - y1 * WW;
    float acc = 0.f;
    for (int y = 0; y < HH; y++) {
        int d = y1 - y;
        acc = fmaf(__expf(-(float)(d * d) * GINV), src[colbase + y * WW], acc);
    }
    // sn[y1][x1] = (sum_y g) * (sum_x g)
    float Sy = 0.f, Sx = 0.f;
    for (int u = 0; u < WW; u++) {
        int dy = y1 - u, dx = x1 - u;
        Sy += __expf(-(float)(dy * dy) * GINV);
        Sx += __expf(-(float)(dx * dx) * GINV);
    }
    dst[idx] = acc / (Sy * Sx);
}

// ---------------- bilateral N^2 pass with on-the-fly kernel ----------------
// Block: 256 threads = 64 i-lanes x 4 j-groups. Grid: (144 tiles, B, ZS).
// Each group stages 64 packed rows (8 KB) into its private LDS slab, then
// inner loop: wave-uniform broadcast reads (ds_read_b128), 5-dim distance,
// one exp, 21 channel FMAs + norm accumulate. Partials written to ws.
__global__ __launch_bounds__(256) void bilateral_kernel(
    const float* __restrict__ pm, float* __restrict__ part)
{
    __shared__ float lds[4][64 * 32];   // 32 KB
    int lane = threadIdx.x & 63;
    int g = threadIdx.x >> 6;
    int tile = blockIdx.x;
    int b = blockIdx.y;
    int z = blockIdx.z;
    int i = tile * 64 + lane;
    const float* pmb = pm + (size_t)b * NN * 32;
    float fr = pmb[i * 32 + 21], fg = pmb[i * 32 + 22], fb2 = pmb[i * 32 + 23];
    float fy = pmb[i * 32 + 24], fx = pmb[i * 32 + 25];
    float acc[22];
#pragma unroll
    for (int c = 0; c < 22; c++) acc[c] = 0.f;
    int j0 = z * JSEG + g * GSEG;
    for (int jc = 0; jc < GSEG; jc += 64) {
        __syncthreads();
        const float4* src = (const float4*)(pmb + (size_t)(j0 + jc) * 32);
        float4* dstl = (float4*)&lds[g][0];
#pragma unroll
        for (int t = 0; t < 8; t++) dstl[t * 64 + lane] = src[t * 64 + lane];
        __syncthreads();
#pragma unroll 4
        for (int jj = 0; jj < 64; jj++) {
            const float4* L = (const float4*)&lds[g][jj * 32];
            float4 v0 = L[0], v1 = L[1], v2 = L[2], v3 = L[3], v4 = L[4], v5 = L[5], v6 = L[6];
            float dr = v5.y - fr, dg = v5.z - fg, db = v5.w - fb2;
            float dy = v6.x - fy, dx = v6.y - fx;
            float nd2 = -(dy * dy);
            nd2 = fmaf(-dx, dx, nd2);
            nd2 = fmaf(-dr, dr, nd2);
            nd2 = fmaf(-dg, dg, nd2);
            nd2 = fmaf(-db, db, nd2);
            float k = __expf(nd2);
            acc[21] += k;
            acc[0]  = fmaf(k, v0.x, acc[0]);  acc[1]  = fmaf(k, v0.y, acc[1]);
            acc[2]  = fmaf(k, v0.z, acc[2]);  acc[3]  = fmaf(k, v0.w, acc[3]);
            acc[4]  = fmaf(k, v1.x, acc[4]);  acc[5]  = fmaf(k, v1.y, acc[5]);
            acc[6]  = fmaf(k, v1.z, acc[6]);  acc[7]  = fmaf(k, v1.w, acc[7]);
            acc[8]  = fmaf(k, v2.x, acc[8]);  acc[9]  = fmaf(k, v2.y, acc[9]);
            acc[10] = fmaf(k, v2.z, acc[10]); acc[11] = fmaf(k, v2.w, acc[11]);
            acc[12] = fmaf(k, v3.x, acc[12]); acc[13] = fmaf(k, v3.y, acc[13]);
            acc[14] = fmaf(k, v3.z, acc[14]); acc[15] = fmaf(k, v3.w, acc[15]);
            acc[16] = fmaf(k, v4.x, acc[16]); acc[17] = fmaf(k, v4.y, acc[17]);
            acc[18] = fmaf(k, v4.z, acc[18]); acc[19] = fmaf(k, v4.w, acc[19]);
            acc[20] = fmaf(k, v5.x, acc[20]);
        }
    }
    // cross-group reduce within block, then write partial for this z
    __syncthreads();
    float* red = &lds[g][0];
#pragma unroll
    for (int c = 0; c < 22; c++) red[c * 64 + lane] = acc[c];
    __syncthreads();
    if (threadIdx.x < 64) {
        int il = threadIdx.x;
        float* outp = part + (((size_t)(z * BB + b) * NTILE + tile) * 22) * 64;
#pragma unroll
        for (int c = 0; c < 22; c++) {
            float t = lds[0][c * 64 + il] + lds[1][c * 64 + il] +
                      lds[2][c * 64 + il] + lds[3][c * 64 + il];
            outp[c * 64 + il] = t;
        }
    }
}

// ---------------- reduce z-partials, divide by bilateral norm --------------
__global__ __launch_bounds__(256) void bil_reduce_kernel(
    const float* __restrict__ part, float* __restrict__ bl)
{
    int idx = blockIdx.x * 256 + threadIdx.x;
    if (idx >= BB * CC * NN) return;
    int b = idx / (CC * NN);
    int r = idx - b * CC * NN;
    int c = r / NN;
    int i = r - c * NN;
    int tile = i >> 6, lane = i & 63;
    float sc = 0.f, sn = 0.f;
#pragma unroll
    for (int z = 0; z < ZS; z++) {
        const float* p = part + (((size_t)(z * BB + b) * NTILE + tile) * 22) * 64;
        sc += p[c * 64 + lane];
        sn += p[21 * 64 + lane];
    }
    bl[idx] = sc / sn;
}

// ---------------- message passing + compatibility + unary update -----------
// q_out layout [B][N][C] == output layout [B,H,W,C]: write directly to d_out.
__global__ __launch_bounds__(256) void update_kernel(
    const float* __restrict__ u, const float* __restrict__ sp,
    const float* __restrict__ bl, const float* __restrict__ Ws,
    const float* __restrict__ Wb, const float* __restrict__ M,
    float* __restrict__ qout)
{
    __shared__ float sWs[441], sWb[441], sM[441];
    for (int t = threadIdx.x; t < 441; t += 256) {
        sWs[t] = Ws[t]; sWb[t] = Wb[t]; sM[t] = M[t];
    }
    __syncthreads();
    int idx = blockIdx.x * 256 + threadIdx.x;
    if (idx >= BB * NN) return;
    int b = idx / NN, i = idx - b * NN;
    const float* spb = sp + (size_t)b * CC * NN + i;
    const float* blb = bl + (size_t)b * CC * NN + i;
    float spv[CC], blv[CC];
#pragma unroll
    for (int c = 0; c < CC; c++) {
        spv[c] = spb[(size_t)c * NN];
        blv[c] = blb[(size_t)c * NN];
    }
    float msg[CC];
#pragma unroll
    for (int c = 0; c < CC; c++) {
        float a = 0.f;
        const float* wr = &sWs[c * CC];
        const float* br = &sWb[c * CC];
#pragma unroll
        for (int c2 = 0; c2 < CC; c2++) a = fmaf(wr[c2], spv[c2], a);
#pragma unroll
        for (int c2 = 0; c2 < CC; c2++) a = fmaf(br[c2], blv[c2], a);
        msg[c] = a;
    }
    const float* up = u + (size_t)idx * CC;
    float* qp = qout + (size_t)idx * CC;
#pragma unroll
    for (int c = 0; c < CC; c++) {
        float a = up[c];
        const float* mr = &sM[c * CC];
#pragma unroll
        for (int c2 = 0; c2 < CC; c2++) a = fmaf(-mr[c2], msg[c2], a);
        qp[c] = a;
    }
}

extern "C" void kernel_launch(void* const* d_in, const int* in_sizes, int n_in,
                              void* d_out, int out_size, void* d_ws, size_t ws_size,
                              hipStream_t stream)
{
    const float* unary = (const float*)d_in[0];  // [B,H,W,C]
    const float* rgb   = (const float*)d_in[1];  // [B,H,W,3]
    const float* Ws    = (const float*)d_in[2];  // [C,C]
    const float* Wb    = (const float*)d_in[3];  // [C,C]
    const float* M     = (const float*)d_in[4];  // [C,C]
    float* out = (float*)d_out;                  // q, [B,N,C]

    float* SM   = (float*)d_ws;                     // B*C*N
    float* PM   = SM  + (size_t)BB * CC * NN;       // B*N*32
    float* TMP  = PM  + (size_t)BB * NN * 32;       // B*C*N
    float* SP   = TMP + (size_t)BB * CC * NN;       // B*C*N
    float* BL   = SP  + (size_t)BB * CC * NN;       // B*C*N
    float* PART = BL  + (size_t)BB * CC * NN;       // ZS*B*144*22*64

    for (int it = 0; it < 5; ++it) {
        const float* qsrc = (it == 0) ? unary : out;
        softmax_pack_kernel<<<dim3((BB * NN + 255) / 256), dim3(256), 0, stream>>>(
            qsrc, rgb, SM, PM);
        spatial_x_kernel<<<dim3((BB * CC * NN + 255) / 256), dim3(256), 0, stream>>>(SM, TMP);
        spatial_y_kernel<<<dim3((BB * CC * NN + 255) / 256), dim3(256), 0, stream>>>(TMP, SP);
        bilateral_kernel<<<dim3(NTILE, BB, ZS), dim3(256), 0, stream>>>(PM, PART);
        bil_reduce_kernel<<<dim3((BB * CC * NN + 255) / 256), dim3(256), 0, stream>>>(PART, BL);
        update_kernel<<<dim3((BB * NN + 255) / 256), dim3(256), 0, stream>>>(
            unary, SP, BL, Ws, Wb, M, out);
    }
}

// Round 2
// 794.741 us; speedup vs baseline: 1.4340x; 1.4340x over previous
//
#include <hip/hip_runtime.h>

#define HH 96
#define WW 96
#define CC 21
#define BB 2
#define NN (HH*WW)          // 9216
#define ZS 6                // j-splits across blockIdx.z
#define JSEG (NN/ZS)        // 1536
#define NT64 (NN/64)        // 144 i-tiles of 64
#define CHUNK 256           // j's staged per LDS chunk
#define SMH_STRIDE 132      // dwords per smh LDS row (128 + 4 pad)

// Feature pre-scale folds both the 1/2 of exp(-d^2/2) and log2(e) so that
// k = exp2(-sum(diff^2)) directly:  s = sqrt(0.5*log2e)/theta
#define KSA2 (0.84932184f / 160.0f)   // bilateral spatial
#define KSB2 (0.84932184f / 3.0f)     // bilateral color
#define GINV (1.0f/18.0f)             // spatial kernel: exp(-d^2/18)

typedef __attribute__((ext_vector_type(4))) float f32x4;
typedef __attribute__((ext_vector_type(8))) short short8;
typedef __attribute__((ext_vector_type(4))) int int4v;

static __device__ inline unsigned pk_bf16(float a, float b) {
    unsigned ua = __builtin_bit_cast(unsigned, a);
    unsigned ub = __builtin_bit_cast(unsigned, b);
    ua += 0x7FFF + ((ua >> 16) & 1);
    ub += 0x7FFF + ((ub >> 16) & 1);
    return (ua >> 16) | (ub & 0xFFFF0000u);
}
static __device__ inline unsigned short bf16_1(float a) {
    unsigned ua = __builtin_bit_cast(unsigned, a);
    ua += 0x7FFF + ((ua >> 16) & 1);
    return (unsigned short)(ua >> 16);
}

// ---------------- softmax over C + write SM (fp32 CN), SMHT (bf16 CN), FJT --
__global__ __launch_bounds__(256) void softmax_pack_kernel(
    const float* __restrict__ q, const float* __restrict__ rgb,
    float* __restrict__ sm_cn, unsigned short* __restrict__ smht,
    float* __restrict__ fjt)
{
    int idx = blockIdx.x * 256 + threadIdx.x;
    if (idx >= BB * NN) return;
    int b = idx / NN, i = idx - b * NN;
    const float* qp = q + (size_t)idx * CC;
    float v[CC];
    float m = -1e30f;
#pragma unroll
    for (int c = 0; c < CC; c++) { v[c] = qp[c]; m = fmaxf(m, v[c]); }
    float s = 0.f;
#pragma unroll
    for (int c = 0; c < CC; c++) { v[c] = __expf(v[c] - m); s += v[c]; }
    float inv = 1.0f / s;
    float* smb = sm_cn + (size_t)b * CC * NN + i;
    unsigned short* shb = smht + (size_t)b * CC * NN + i;
#pragma unroll
    for (int c = 0; c < CC; c++) {
        float sv = v[c] * inv;
        smb[(size_t)c * NN] = sv;
        shb[(size_t)c * NN] = bf16_1(sv);
    }
    const float* rp = rgb + (size_t)idx * 3;
    float* fb = fjt + (size_t)b * 5 * NN;
    int y = i / WW, x = i - y * WW;
    fb[0 * NN + i] = rp[0] * KSB2;
    fb[1 * NN + i] = rp[1] * KSB2;
    fb[2 * NN + i] = rp[2] * KSB2;
    fb[3 * NN + i] = (float)y * KSA2;
    fb[4 * NN + i] = (float)x * KSA2;
}

// ---------------- separable spatial Gaussian, pass 1 (along x) -------------
__global__ __launch_bounds__(256) void spatial_x_kernel(
    const float* __restrict__ src, float* __restrict__ dst)
{
    int idx = blockIdx.x * 256 + threadIdx.x;
    if (idx >= BB * CC * NN) return;
    int x1 = idx % WW;
    int rowbase = idx - x1;
    float acc = 0.f;
    for (int x = 0; x < WW; x++) {
        int d = x1 - x;
        acc = fmaf(__expf(-(float)(d * d) * GINV), src[rowbase + x], acc);
    }
    dst[idx] = acc;
}

// ---------------- pass 2 (along y) + analytic normalization ----------------
__global__ __launch_bounds__(256) void spatial_y_kernel(
    const float* __restrict__ src, float* __restrict__ dst)
{
    int idx = blockIdx.x * 256 + threadIdx.x;
    if (idx >= BB * CC * NN) return;
    int x1 = idx % WW;
    int y1 = (idx / WW) % HH;
    int colbase = idx - y1 * WW;
    float acc = 0.f;
    for (int y = 0; y < HH; y++) {
        int d = y1 - y;
        acc = fmaf(__expf(-(float)(d * d) * GINV), src[colbase + y * WW], acc);
    }
    float Sy = 0.f, Sx = 0.f;
    for (int u = 0; u < WW; u++) {
        int dy = y1 - u, dx = x1 - u;
        Sy += __expf(-(float)(dy * dy) * GINV);
        Sx += __expf(-(float)(dx * dx) * GINV);
    }
    dst[idx] = acc / (Sy * Sx);
}

// ---------------- bilateral N^2 pass: VALU exp -> bf16 MFMA accumulate -----
// Block: 256 thr = 4 waves. Wave w owns 16 i's (block covers 64 i).
// K-tile: A[m=i(lane&15)][k=j(quad*8+e)] computed in regs; B = smhT from LDS.
// D[i][c] accumulates over the block's whole z-slice of j.
__global__ __launch_bounds__(256) void bilateral_kernel(
    const unsigned short* __restrict__ smht,  // [B][21][N] bf16
    const float* __restrict__ fjt,            // [B][5][N]
    float* __restrict__ part)                 // [ZS*B][N][24]
{
    __shared__ unsigned lds_smh[32 * SMH_STRIDE];  // 16.9 KB
    __shared__ float lds_fj[5 * CHUNK];            // 5 KB
    int tid = threadIdx.x;
    int lane = tid & 63, w = tid >> 6;
    int quad = lane >> 4, l16 = lane & 15;
    int tile = blockIdx.x, b = blockIdx.y, z = blockIdx.z;
    int i = tile * 64 + w * 16 + l16;
    const float* fb = fjt + (size_t)b * 5 * NN;
    float fi0 = fb[0 * NN + i], fi1 = fb[1 * NN + i], fi2 = fb[2 * NN + i];
    float fi3 = fb[3 * NN + i], fi4 = fb[4 * NN + i];
    f32x4 acc0 = {0.f, 0.f, 0.f, 0.f};
    f32x4 acc1 = {0.f, 0.f, 0.f, 0.f};
    const unsigned* smg = (const unsigned*)smht + (size_t)b * CC * (NN / 2);

    for (int chunk = 0; chunk < JSEG / CHUNK; chunk++) {
        int j0 = z * JSEG + chunk * CHUNK;
        __syncthreads();
        // stage smhT chunk: rows 0..20 real, row 21 = 1.0 (norm), 22..31 = 0
        for (int idx = tid; idx < 32 * (CHUNK / 2); idx += 256) {
            int row = idx >> 7, col = idx & 127;
            unsigned vv;
            if (row < 21)      vv = smg[(size_t)row * (NN / 2) + (j0 >> 1) + col];
            else if (row == 21) vv = 0x3F803F80u;
            else                vv = 0u;
            lds_smh[row * SMH_STRIDE + col] = vv;
        }
        // stage j-features
        for (int idx = tid; idx < 5 * CHUNK; idx += 256) {
            int row = idx >> 8, col = idx & 255;
            lds_fj[idx] = fb[(size_t)row * NN + j0 + col];
        }
        __syncthreads();

        for (int jb = 0; jb < CHUNK / 32; jb++) {
            int coff = jb * 32 + quad * 8;
            float vf[5][8];
#pragma unroll
            for (int ft = 0; ft < 5; ft++) {
                const float4* p = (const float4*)&lds_fj[ft * CHUNK + coff];
                float4 lo = p[0], hi = p[1];
                vf[ft][0] = lo.x; vf[ft][1] = lo.y; vf[ft][2] = lo.z; vf[ft][3] = lo.w;
                vf[ft][4] = hi.x; vf[ft][5] = hi.y; vf[ft][6] = hi.z; vf[ft][7] = hi.w;
            }
            float kf[8];
#pragma unroll
            for (int e = 0; e < 8; e++) {
                float d0 = vf[0][e] - fi0;
                float d1 = vf[1][e] - fi1;
                float d2 = vf[2][e] - fi2;
                float d3 = vf[3][e] - fi3;
                float d4 = vf[4][e] - fi4;
                float s = d0 * d0;
                s = fmaf(d1, d1, s);
                s = fmaf(d2, d2, s);
                s = fmaf(d3, d3, s);
                s = fmaf(d4, d4, s);
                kf[e] = __builtin_amdgcn_exp2f(-s);
            }
            int4v ap = { (int)pk_bf16(kf[0], kf[1]), (int)pk_bf16(kf[2], kf[3]),
                         (int)pk_bf16(kf[4], kf[5]), (int)pk_bf16(kf[6], kf[7]) };
            short8 afrag = __builtin_bit_cast(short8, ap);
            int bd = jb * 16 + quad * 4;
            short8 b0 = *(const short8*)&lds_smh[l16 * SMH_STRIDE + bd];
            short8 b1 = *(const short8*)&lds_smh[(16 + l16) * SMH_STRIDE + bd];
            acc0 = __builtin_amdgcn_mfma_f32_16x16x32_bf16(afrag, b0, acc0, 0, 0, 0);
            acc1 = __builtin_amdgcn_mfma_f32_16x16x32_bf16(afrag, b1, acc1, 0, 0, 0);
        }
    }
    // epilogue: lane holds D[row=quad*4+r][col=l16] for this wave's 16-i tile
    float* pr = part + (size_t)(z * BB + b) * NN * 24;
    int ibase = tile * 64 + w * 16 + quad * 4;
#pragma unroll
    for (int r = 0; r < 4; r++)
        pr[(size_t)(ibase + r) * 24 + l16] = acc0[r];
    if (l16 < 6) {
#pragma unroll
        for (int r = 0; r < 4; r++)
            pr[(size_t)(ibase + r) * 24 + 16 + l16] = acc1[r];
    }
}

// ------- z-reduce partials + bilateral norm + message passing + update -----
__global__ __launch_bounds__(256) void update_kernel(
    const float* __restrict__ u, const float* __restrict__ sp,
    const float* __restrict__ part, const float* __restrict__ Ws,
    const float* __restrict__ Wb, const float* __restrict__ M,
    float* __restrict__ qout)
{
    __shared__ float sWs[441], sWb[441], sM[441];
    for (int t = threadIdx.x; t < 441; t += 256) {
        sWs[t] = Ws[t]; sWb[t] = Wb[t]; sM[t] = M[t];
    }
    __syncthreads();
    int idx = blockIdx.x * 256 + threadIdx.x;
    if (idx >= BB * NN) return;
    int b = idx / NN, i = idx - b * NN;
    // reduce bilateral partials over z
    float blv[22];
#pragma unroll
    for (int c = 0; c < 22; c++) blv[c] = 0.f;
#pragma unroll
    for (int z = 0; z < ZS; z++) {
        const float* p = part + (size_t)(z * BB + b) * NN * 24 + (size_t)i * 24;
#pragma unroll
        for (int c = 0; c < 22; c++) blv[c] += p[c];
    }
    float ninv = 1.0f / blv[21];
#pragma unroll
    for (int c = 0; c < CC; c++) blv[c] *= ninv;
    const float* spb = sp + (size_t)b * CC * NN + i;
    float spv[CC];
#pragma unroll
    for (int c = 0; c < CC; c++) spv[c] = spb[(size_t)c * NN];
    float msg[CC];
#pragma unroll
    for (int c = 0; c < CC; c++) {
        float a = 0.f;
        const float* wr = &sWs[c * CC];
        const float* br = &sWb[c * CC];
#pragma unroll
        for (int c2 = 0; c2 < CC; c2++) a = fmaf(wr[c2], spv[c2], a);
#pragma unroll
        for (int c2 = 0; c2 < CC; c2++) a = fmaf(br[c2], blv[c2], a);
        msg[c] = a;
    }
    const float* up = u + (size_t)idx * CC;
    float* qp = qout + (size_t)idx * CC;
#pragma unroll
    for (int c = 0; c < CC; c++) {
        float a = up[c];
        const float* mr = &sM[c * CC];
#pragma unroll
        for (int c2 = 0; c2 < CC; c2++) a = fmaf(-mr[c2], msg[c2], a);
        qp[c] = a;
    }
}

extern "C" void kernel_launch(void* const* d_in, const int* in_sizes, int n_in,
                              void* d_out, int out_size, void* d_ws, size_t ws_size,
                              hipStream_t stream)
{
    const float* unary = (const float*)d_in[0];  // [B,H,W,C]
    const float* rgb   = (const float*)d_in[1];  // [B,H,W,3]
    const float* Ws    = (const float*)d_in[2];  // [C,C]
    const float* Wb    = (const float*)d_in[3];  // [C,C]
    const float* M     = (const float*)d_in[4];  // [C,C]
    float* out = (float*)d_out;                  // q, [B,N,C]

    float* SM   = (float*)d_ws;                         // B*C*N
    float* TMP  = SM   + (size_t)BB * CC * NN;          // B*C*N
    float* SP   = TMP  + (size_t)BB * CC * NN;          // B*C*N
    float* FJT  = SP   + (size_t)BB * CC * NN;          // B*5*N
    float* PART = FJT  + (size_t)BB * 5 * NN;           // ZS*B*N*24
    unsigned short* SMHT = (unsigned short*)(PART + (size_t)ZS * BB * NN * 24); // B*21*N bf16

    for (int it = 0; it < 5; ++it) {
        const float* qsrc = (it == 0) ? unary : out;
        softmax_pack_kernel<<<dim3((BB * NN + 255) / 256), dim3(256), 0, stream>>>(
            qsrc, rgb, SM, SMHT, FJT);
        spatial_x_kernel<<<dim3((BB * CC * NN + 255) / 256), dim3(256), 0, stream>>>(SM, TMP);
        spatial_y_kernel<<<dim3((BB * CC * NN + 255) / 256), dim3(256), 0, stream>>>(TMP, SP);
        bilateral_kernel<<<dim3(NT64, BB, ZS), dim3(256), 0, stream>>>(SMHT, FJT, PART);
        update_kernel<<<dim3((BB * NN + 255) / 256), dim3(256), 0, stream>>>(
            unary, SP, PART, Ws, Wb, M, out);
    }
}

// Round 3
// 729.952 us; speedup vs baseline: 1.5612x; 1.0888x over previous
//
#include <hip/hip_runtime.h>

#define HH 96
#define WW 96
#define CC 21
#define BB 2
#define NN (HH*WW)          // 9216
#define NT16 (NN/16)        // 576 sorted 16-tiles per batch
#define NJB  (NN/32)        // 288 sorted 32-j-blocks per batch
#define ZS 9                // mask dwords per tile (288/32)
#define PRUNE_T 24.0f       // exp2-domain skip threshold

// feature pre-scale folds 1/2 and log2(e): k = exp2(-sum(diff^2))
#define KSA2 (0.84932184f / 160.0f)   // bilateral spatial
#define KSB2 (0.84932184f / 3.0f)     // bilateral color
#define GL2  (1.44269504f / 18.0f)    // spatial kernel exp(-d^2/18) in exp2

typedef __attribute__((ext_vector_type(4))) float f32x4;
typedef __attribute__((ext_vector_type(8))) short short8;
typedef __attribute__((ext_vector_type(4))) int int4v;

static __device__ inline unsigned pk_bf16(float a, float b) {
    unsigned ua = __builtin_bit_cast(unsigned, a);
    unsigned ub = __builtin_bit_cast(unsigned, b);
    ua += 0x7FFF + ((ua >> 16) & 1);
    ub += 0x7FFF + ((ub >> 16) & 1);
    return (ua >> 16) | (ub & 0xFFFF0000u);
}
static __device__ inline unsigned short bf16_1(float a) {
    unsigned ua = __builtin_bit_cast(unsigned, a);
    ua += 0x7FFF + ((ua >> 16) & 1);
    return (unsigned short)(ua >> 16);
}

// ---------------- P0: 1D gaussian table + row-sum table --------------------
__global__ __launch_bounds__(128) void tables_kernel(float* __restrict__ gtab,
                                                     float* __restrict__ sxt)
{
    __shared__ float gt[96];
    int t = threadIdx.x;
    if (t < 96) {
        float g = __builtin_amdgcn_exp2f(-(float)(t * t) * GL2);
        gt[t] = g; gtab[t] = g;
    }
    __syncthreads();
    if (t < 96) {
        float s = 0.f;
        for (int v = 0; v < 96; v++) s += gt[abs(t - v)];
        sxt[t] = s;
    }
}

// ---------------- P0b: constant rows of sorted bf16 softmax matrix ---------
// rows 21 (=1.0 for norm) and 22..31 (=0) of smht_s[B][32][N]
__global__ __launch_bounds__(256) void fill_kernel(unsigned short* __restrict__ smht)
{
    int idx = blockIdx.x * 256 + threadIdx.x;
    if (idx >= BB * 11 * NN) return;
    int b = idx / (11 * NN);
    int rem = idx - b * 11 * NN;
    int r = rem / NN, col = rem - r * NN;
    smht[(size_t)(b * 32 + 21 + r) * NN + col] = (r == 0) ? 0x3F80 : 0;
}

// ---------------- P1: counting sort by 12-bit color cell -------------------
// one block per batch. Writes spos (pixel -> sorted pos) and sorted scaled
// bilateral features fjs[B][5][N] (r,g,b,y,x).
__global__ __launch_bounds__(256) void sort_kernel(
    const float* __restrict__ rgb, int* __restrict__ spos, float* __restrict__ fjs)
{
    __shared__ int hist[4096];
    __shared__ int psum[256];
    int b = blockIdx.x, t = threadIdx.x;
    for (int k = t; k < 4096; k += 256) hist[k] = 0;
    __syncthreads();
    for (int p = t; p < NN; p += 256) {
        const float* rp = rgb + (size_t)(b * NN + p) * 3;
        int cr = min(15, (int)rp[0] >> 4);
        int cg = min(15, (int)rp[1] >> 4);
        int cb = min(15, (int)rp[2] >> 4);
        atomicAdd(&hist[(cr << 8) | (cg << 4) | cb], 1);
    }
    __syncthreads();
    int base = t * 16, s = 0;
    for (int k = 0; k < 16; k++) s += hist[base + k];
    psum[t] = s;
    __syncthreads();
    for (int off = 1; off < 256; off <<= 1) {
        int add = (t >= off) ? psum[t - off] : 0;
        __syncthreads();
        psum[t] += add;
        __syncthreads();
    }
    int run = psum[t] - s;  // exclusive prefix of this thread's 16 bins
    for (int k = 0; k < 16; k++) { int h = hist[base + k]; hist[base + k] = run; run += h; }
    __syncthreads();
    float* fb = fjs + (size_t)b * 5 * NN;
    for (int p = t; p < NN; p += 256) {
        const float* rp = rgb + (size_t)(b * NN + p) * 3;
        float r = rp[0], g = rp[1], bl = rp[2];
        int cr = min(15, (int)r >> 4);
        int cg = min(15, (int)g >> 4);
        int cb = min(15, (int)bl >> 4);
        int pos = atomicAdd(&hist[(cr << 8) | (cg << 4) | cb], 1);
        spos[b * NN + p] = pos;
        int y = p / WW, x = p - y * WW;
        fb[0 * NN + pos] = r * KSB2;
        fb[1 * NN + pos] = g * KSB2;
        fb[2 * NN + pos] = bl * KSB2;
        fb[3 * NN + pos] = (float)y * KSA2;
        fb[4 * NN + pos] = (float)x * KSA2;
    }
}

// ---------------- P2a: color bbox per sorted 16-tile -----------------------
__global__ __launch_bounds__(256) void bounds_kernel(
    const float* __restrict__ fjs, float* __restrict__ bnd)
{
    int idx = blockIdx.x * 256 + threadIdx.x;
    if (idx >= BB * NT16) return;
    int b = idx / NT16, tile = idx - b * NT16;
    const float* fb = fjs + (size_t)b * 5 * NN + tile * 16;
    float lo[3], hi[3];
#pragma unroll
    for (int f = 0; f < 3; f++) { lo[f] = 1e30f; hi[f] = -1e30f; }
    for (int k = 0; k < 16; k++) {
#pragma unroll
        for (int f = 0; f < 3; f++) {
            float v = fb[f * NN + k];
            lo[f] = fminf(lo[f], v); hi[f] = fmaxf(hi[f], v);
        }
    }
    float* o = bnd + (size_t)idx * 6;
#pragma unroll
    for (int f = 0; f < 3; f++) { o[2 * f] = lo[f]; o[2 * f + 1] = hi[f]; }
}

// ---------------- P2b: 288-bit skip mask per (b, tile16) -------------------
__global__ __launch_bounds__(256) void mask_kernel(
    const float* __restrict__ bnd, unsigned* __restrict__ mask)
{
    int idx = blockIdx.x * 256 + threadIdx.x;
    if (idx >= BB * NT16 * ZS) return;
    int z = idx % ZS;
    int bt = idx / ZS;
    int b = bt / NT16, tile = bt - b * NT16;
    const float* tb = bnd + (size_t)(b * NT16 + tile) * 6;
    float tlo0 = tb[0], thi0 = tb[1], tlo1 = tb[2], thi1 = tb[3], tlo2 = tb[4], thi2 = tb[5];
    unsigned m = 0;
    for (int bit = 0; bit < 32; bit++) {
        int jb = z * 32 + bit;
        const float* a0 = bnd + (size_t)(b * NT16 + 2 * jb) * 6;
        const float* a1 = bnd + (size_t)(b * NT16 + 2 * jb + 1) * 6;
        float s = 0.f;
#pragma unroll
        for (int f = 0; f < 3; f++) {
            float jlo = fminf(a0[2 * f], a1[2 * f]);
            float jhi = fmaxf(a0[2 * f + 1], a1[2 * f + 1]);
            float lo = (f == 0) ? tlo0 : (f == 1) ? tlo1 : tlo2;
            float hi = (f == 0) ? thi0 : (f == 1) ? thi1 : thi2;
            float gap = fmaxf(0.f, fmaxf(lo - jhi, jlo - hi));
            s = fmaf(gap, gap, s);
        }
        if (s <= PRUNE_T) m |= (1u << bit);
    }
    mask[(size_t)bt * ZS + z] = m;
}

// ---------------- K1: softmax + scatter sorted bf16 + spatial x-conv -------
// block = one (b, y) image row, 128 threads. Also zeroes PART for this row.
__global__ __launch_bounds__(128) void softmax_sx_kernel(
    const float* __restrict__ q, const int* __restrict__ spos,
    const float* __restrict__ gtab, unsigned short* __restrict__ smht,
    float* __restrict__ tmp, float* __restrict__ part)
{
    __shared__ float smL[21 * 96];
    __shared__ float gt[96];
    int blk = blockIdx.x;
    int b = blk / HH, y = blk - b * HH;
    int t = threadIdx.x;
    if (t < 96) gt[t] = gtab[t];
    if (t < 96) {
        int p = y * WW + t;
        int idx = b * NN + p;
        const float* qp = q + (size_t)idx * CC;
        float v[CC], m = -1e30f;
#pragma unroll
        for (int c = 0; c < CC; c++) { v[c] = qp[c]; m = fmaxf(m, v[c]); }
        float ssum = 0.f;
#pragma unroll
        for (int c = 0; c < CC; c++) { v[c] = __expf(v[c] - m); ssum += v[c]; }
        float inv = 1.0f / ssum;
        int s = spos[idx];
#pragma unroll
        for (int c = 0; c < CC; c++) {
            float sv = v[c] * inv;
            smL[c * 96 + t] = sv;
            smht[(size_t)(b * 32 + c) * NN + s] = bf16_1(sv);
        }
        float* pp = part + (size_t)(b * NN + s) * 24;
#pragma unroll
        for (int k = 0; k < 24; k++) pp[k] = 0.f;
    }
    __syncthreads();
    for (int o = t; o < 21 * 96; o += 128) {
        int c = o / 96, x = o - c * 96;
        const float* row = &smL[c * 96];
        float acc = 0.f;
        for (int xp = 0; xp < 96; xp++)
            acc = fmaf(gt[abs(x - xp)], row[xp], acc);
        tmp[(size_t)((b * CC + c) * HH + y) * WW + x] = acc;
    }
}

// ---------------- K2: sparse bilateral via skip mask + MFMA ----------------
// grid (144, B, ZS), 256 thr = 4 waves; wave w owns sorted 16-i tile.
__global__ __launch_bounds__(256) void bilateral_sparse_kernel(
    const unsigned short* __restrict__ smht, const float* __restrict__ fjs,
    const unsigned* __restrict__ mask, float* __restrict__ part)
{
    int tid = threadIdx.x;
    int lane = tid & 63, w = tid >> 6;
    int quad = lane >> 4, l16 = lane & 15;
    int b = blockIdx.y, z = blockIdx.z;
    int tile16 = blockIdx.x * 4 + w;
    int i = tile16 * 16 + l16;
    const float* fb = fjs + (size_t)b * 5 * NN;
    float fi0 = fb[0 * NN + i], fi1 = fb[1 * NN + i], fi2 = fb[2 * NN + i];
    float fi3 = fb[3 * NN + i], fi4 = fb[4 * NN + i];
    f32x4 acc0 = {0.f, 0.f, 0.f, 0.f};
    f32x4 acc1 = {0.f, 0.f, 0.f, 0.f};
    const unsigned short* smb = smht + (size_t)b * 32 * NN;
    unsigned m = mask[(size_t)(b * NT16 + tile16) * ZS + z];
    while (m) {
        int bit = __ffs(m) - 1;
        m &= m - 1;
        int j0 = (z * 32 + bit) * 32;
        int coff = j0 + quad * 8;
        float vf[5][8];
#pragma unroll
        for (int f = 0; f < 5; f++) {
            const float4* pf = (const float4*)(fb + (size_t)f * NN + coff);
            float4 lo = pf[0], hi = pf[1];
            vf[f][0] = lo.x; vf[f][1] = lo.y; vf[f][2] = lo.z; vf[f][3] = lo.w;
            vf[f][4] = hi.x; vf[f][5] = hi.y; vf[f][6] = hi.z; vf[f][7] = hi.w;
        }
        float kf[8];
#pragma unroll
        for (int e = 0; e < 8; e++) {
            float d0 = vf[0][e] - fi0;
            float d1 = vf[1][e] - fi1;
            float d2 = vf[2][e] - fi2;
            float d3 = vf[3][e] - fi3;
            float d4 = vf[4][e] - fi4;
            float s = d0 * d0;
            s = fmaf(d1, d1, s);
            s = fmaf(d2, d2, s);
            s = fmaf(d3, d3, s);
            s = fmaf(d4, d4, s);
            kf[e] = __builtin_amdgcn_exp2f(-s);
        }
        int4v ap = { (int)pk_bf16(kf[0], kf[1]), (int)pk_bf16(kf[2], kf[3]),
                     (int)pk_bf16(kf[4], kf[5]), (int)pk_bf16(kf[6], kf[7]) };
        short8 afrag = __builtin_bit_cast(short8, ap);
        short8 b0 = *(const short8*)(smb + (size_t)l16 * NN + coff);
        short8 b1 = *(const short8*)(smb + (size_t)(16 + l16) * NN + coff);
        acc0 = __builtin_amdgcn_mfma_f32_16x16x32_bf16(afrag, b0, acc0, 0, 0, 0);
        acc1 = __builtin_amdgcn_mfma_f32_16x16x32_bf16(afrag, b1, acc1, 0, 0, 0);
    }
    // D[row=i=quad*4+r][col=c=l16]; scatter-add into PART (z waves collide)
    int ibase = tile16 * 16 + quad * 4;
    float* pr = part + (size_t)b * NN * 24;
#pragma unroll
    for (int r = 0; r < 4; r++)
        atomicAdd(&pr[(size_t)(ibase + r) * 24 + l16], acc0[r]);
    if (l16 < 6) {
#pragma unroll
        for (int r = 0; r < 4; r++)
            atomicAdd(&pr[(size_t)(ibase + r) * 24 + 16 + l16], acc1[r]);
    }
}

// ---------------- K3: spatial y-conv + norm + messages + update ------------
// block = one (b, x) image column, 128 threads.
__global__ __launch_bounds__(128) void sy_update_kernel(
    const float* __restrict__ u, const float* __restrict__ tmp,
    const float* __restrict__ part, const int* __restrict__ spos,
    const float* __restrict__ gtab, const float* __restrict__ sxt,
    const float* __restrict__ Ws, const float* __restrict__ Wb,
    const float* __restrict__ M, float* __restrict__ qout)
{
    __shared__ float slab[21 * 96];   // tmp[:, :, x] column
    __shared__ float spc[21 * 96];    // spatial-filtered, normalized
    __shared__ float gt[96], sx[96];
    __shared__ float sWs[441], sWb[441], sM[441];
    int blk = blockIdx.x;
    int b = blk / WW, x = blk - b * WW;
    int t = threadIdx.x;
    if (t < 96) { gt[t] = gtab[t]; sx[t] = sxt[t]; }
    for (int o = t; o < 441; o += 128) { sWs[o] = Ws[o]; sWb[o] = Wb[o]; sM[o] = M[o]; }
    for (int o = t; o < 21 * 96; o += 128) {
        int c = o / 96, yp = o - c * 96;
        slab[o] = tmp[(size_t)((b * CC + c) * HH + yp) * WW + x];
    }
    __syncthreads();
    float sxx = sx[x];
    for (int o = t; o < 21 * 96; o += 128) {
        int c = o / 96, y = o - c * 96;
        const float* col = &slab[c * 96];
        float acc = 0.f;
        for (int yp = 0; yp < 96; yp++)
            acc = fmaf(gt[abs(y - yp)], col[yp], acc);
        spc[o] = acc / (sx[y] * sxx);
    }
    __syncthreads();
    if (t < 96) {
        int y = t, p = y * WW + x;
        int idx = b * NN + p;
        const float* pp = part + (size_t)(b * NN + spos[idx]) * 24;
        float blv[22];
#pragma unroll
        for (int c = 0; c < 22; c++) blv[c] = pp[c];
        float ninv = 1.0f / blv[21];
        float spv[CC], msg[CC];
#pragma unroll
        for (int c = 0; c < CC; c++) { blv[c] *= ninv; spv[c] = spc[c * 96 + y]; }
#pragma unroll
        for (int c = 0; c < CC; c++) {
            float a = 0.f;
            const float* wr = &sWs[c * CC];
            const float* br = &sWb[c * CC];
#pragma unroll
            for (int c2 = 0; c2 < CC; c2++) a = fmaf(wr[c2], spv[c2], a);
#pragma unroll
            for (int c2 = 0; c2 < CC; c2++) a = fmaf(br[c2], blv[c2], a);
            msg[c] = a;
        }
        const float* up = u + (size_t)idx * CC;
        float* qp = qout + (size_t)idx * CC;
#pragma unroll
        for (int c = 0; c < CC; c++) {
            float a = up[c];
            const float* mr = &sM[c * CC];
#pragma unroll
            for (int c2 = 0; c2 < CC; c2++) a = fmaf(-mr[c2], msg[c2], a);
            qp[c] = a;
        }
    }
}

extern "C" void kernel_launch(void* const* d_in, const int* in_sizes, int n_in,
                              void* d_out, int out_size, void* d_ws, size_t ws_size,
                              hipStream_t stream)
{
    const float* unary = (const float*)d_in[0];  // [B,H,W,C]
    const float* rgb   = (const float*)d_in[1];  // [B,H,W,3]
    const float* Ws    = (const float*)d_in[2];
    const float* Wb    = (const float*)d_in[3];
    const float* M     = (const float*)d_in[4];
    float* out = (float*)d_out;                  // [B,N,C]

    float* GTAB = (float*)d_ws;                          // 96
    float* SXT  = GTAB + 96;                             // 96
    float* FJS  = SXT + 96;                              // B*5*N
    float* TMP  = FJS + (size_t)BB * 5 * NN;             // B*21*N
    float* PART = TMP + (size_t)BB * CC * NN;            // B*N*24
    float* BND  = PART + (size_t)BB * NN * 24;           // B*576*6
    int*   SPOS = (int*)(BND + (size_t)BB * NT16 * 6);   // B*N
    unsigned* MASK = (unsigned*)(SPOS + BB * NN);        // B*576*9
    unsigned short* SMHT = (unsigned short*)(MASK + (size_t)BB * NT16 * ZS); // B*32*N

    tables_kernel<<<1, 128, 0, stream>>>(GTAB, SXT);
    fill_kernel<<<(BB * 11 * NN + 255) / 256, 256, 0, stream>>>(SMHT);
    sort_kernel<<<BB, 256, 0, stream>>>(rgb, SPOS, FJS);
    bounds_kernel<<<(BB * NT16 + 255) / 256, 256, 0, stream>>>(FJS, BND);
    mask_kernel<<<(BB * NT16 * ZS + 255) / 256, 256, 0, stream>>>(BND, MASK);

    for (int it = 0; it < 5; ++it) {
        const float* qsrc = (it == 0) ? unary : out;
        softmax_sx_kernel<<<BB * HH, 128, 0, stream>>>(qsrc, SPOS, GTAB, SMHT, TMP, PART);
        bilateral_sparse_kernel<<<dim3(NT16 / 4, BB, ZS), 256, 0, stream>>>(SMHT, FJS, MASK, PART);
        sy_update_kernel<<<BB * WW, 128, 0, stream>>>(unary, TMP, PART, SPOS, GTAB, SXT,
                                                      Ws, Wb, M, out);
    }
}

// Round 4
// 435.141 us; speedup vs baseline: 2.6190x; 1.6775x over previous
//
#include <hip/hip_runtime.h>

#define HH 96
#define WW 96
#define CC 21
#define BB 2
#define NN (HH*WW)          // 9216
#define NT16 (NN/16)        // 576 sorted 16-tiles per batch
#define ZS 9                // mask dwords per tile (288 j-blocks / 32)
#define PRUNE_T 24.0f       // exp2-domain skip threshold
#define GST 104             // LDS row stride (elements) for 96-wide bf16 rows

// feature pre-scale folds 1/2 and log2(e): k = exp2(-sum(diff^2))
#define KSA2 (0.84932184f / 160.0f)   // bilateral spatial
#define KSB2 (0.84932184f / 3.0f)     // bilateral color
#define GL2  (1.44269504f / 18.0f)    // spatial kernel exp(-d^2/18) in exp2 units

typedef __attribute__((ext_vector_type(4))) float f32x4;
typedef __attribute__((ext_vector_type(8))) short short8;
typedef __attribute__((ext_vector_type(4))) int int4v;

static __device__ inline unsigned pk_bf16(float a, float b) {
    unsigned ua = __builtin_bit_cast(unsigned, a);
    unsigned ub = __builtin_bit_cast(unsigned, b);
    ua += 0x7FFF + ((ua >> 16) & 1);
    ub += 0x7FFF + ((ub >> 16) & 1);
    return (ua >> 16) | (ub & 0xFFFF0000u);
}
static __device__ inline unsigned short bf16_1(float a) {
    unsigned ua = __builtin_bit_cast(unsigned, a);
    ua += 0x7FFF + ((ua >> 16) & 1);
    return (unsigned short)(ua >> 16);
}

// ---------------- P0: Gaussian matrix (bf16) + 1D row-sum table ------------
__global__ __launch_bounds__(128) void tables_kernel(
    float* __restrict__ sxt, unsigned short* __restrict__ gbt)
{
    __shared__ float gt[96];
    int t = threadIdx.x;
    if (t < 96) gt[t] = __builtin_amdgcn_exp2f(-(float)(t * t) * GL2);
    __syncthreads();
    if (t < 96) {
        float s = 0.f;
        for (int v = 0; v < 96; v++) s += gt[abs(t - v)];
        sxt[t] = s;
        for (int v = 0; v < 96; v++) gbt[t * 96 + v] = bf16_1(gt[abs(t - v)]);
    }
}

// ---------------- P0b: constant rows 21..31 of sorted bf16 softmax ---------
__global__ __launch_bounds__(256) void fill_kernel(unsigned short* __restrict__ smht)
{
    int idx = blockIdx.x * 256 + threadIdx.x;
    if (idx >= BB * 11 * NN) return;
    int b = idx / (11 * NN);
    int rem = idx - b * 11 * NN;
    int r = rem / NN, col = rem - r * NN;
    smht[(size_t)(b * 32 + 21 + r) * NN + col] = (r == 0) ? 0x3F80 : 0;
}

// ---------------- P1: counting sort by 12-bit color cell -------------------
__global__ __launch_bounds__(256) void sort_kernel(
    const float* __restrict__ rgb, int* __restrict__ spos, float* __restrict__ fjs)
{
    __shared__ int hist[4096];
    __shared__ int psum[256];
    int b = blockIdx.x, t = threadIdx.x;
    for (int k = t; k < 4096; k += 256) hist[k] = 0;
    __syncthreads();
    for (int p = t; p < NN; p += 256) {
        const float* rp = rgb + (size_t)(b * NN + p) * 3;
        int cr = min(15, (int)rp[0] >> 4);
        int cg = min(15, (int)rp[1] >> 4);
        int cb = min(15, (int)rp[2] >> 4);
        atomicAdd(&hist[(cr << 8) | (cg << 4) | cb], 1);
    }
    __syncthreads();
    int base = t * 16, s = 0;
    for (int k = 0; k < 16; k++) s += hist[base + k];
    psum[t] = s;
    __syncthreads();
    for (int off = 1; off < 256; off <<= 1) {
        int add = (t >= off) ? psum[t - off] : 0;
        __syncthreads();
        psum[t] += add;
        __syncthreads();
    }
    int run = psum[t] - s;
    for (int k = 0; k < 16; k++) { int h = hist[base + k]; hist[base + k] = run; run += h; }
    __syncthreads();
    float* fb = fjs + (size_t)b * 5 * NN;
    for (int p = t; p < NN; p += 256) {
        const float* rp = rgb + (size_t)(b * NN + p) * 3;
        float r = rp[0], g = rp[1], bl = rp[2];
        int cr = min(15, (int)r >> 4);
        int cg = min(15, (int)g >> 4);
        int cb = min(15, (int)bl >> 4);
        int pos = atomicAdd(&hist[(cr << 8) | (cg << 4) | cb], 1);
        spos[b * NN + p] = pos;
        int y = p / WW, x = p - y * WW;
        fb[0 * NN + pos] = r * KSB2;
        fb[1 * NN + pos] = g * KSB2;
        fb[2 * NN + pos] = bl * KSB2;
        fb[3 * NN + pos] = (float)y * KSA2;
        fb[4 * NN + pos] = (float)x * KSA2;
    }
}

// ---------------- P2a: color bbox per sorted 16-tile -----------------------
__global__ __launch_bounds__(256) void bounds_kernel(
    const float* __restrict__ fjs, float* __restrict__ bnd)
{
    int idx = blockIdx.x * 256 + threadIdx.x;
    if (idx >= BB * NT16) return;
    int b = idx / NT16, tile = idx - b * NT16;
    const float* fb = fjs + (size_t)b * 5 * NN + tile * 16;
    float lo[3], hi[3];
#pragma unroll
    for (int f = 0; f < 3; f++) { lo[f] = 1e30f; hi[f] = -1e30f; }
    for (int k = 0; k < 16; k++) {
#pragma unroll
        for (int f = 0; f < 3; f++) {
            float v = fb[f * NN + k];
            lo[f] = fminf(lo[f], v); hi[f] = fmaxf(hi[f], v);
        }
    }
    float* o = bnd + (size_t)idx * 6;
#pragma unroll
    for (int f = 0; f < 3; f++) { o[2 * f] = lo[f]; o[2 * f + 1] = hi[f]; }
}

// ---------------- P2b: 288-bit skip mask per (b, tile16) -------------------
__global__ __launch_bounds__(256) void mask_kernel(
    const float* __restrict__ bnd, unsigned* __restrict__ mask)
{
    int idx = blockIdx.x * 256 + threadIdx.x;
    if (idx >= BB * NT16 * ZS) return;
    int z = idx % ZS;
    int bt = idx / ZS;
    int b = bt / NT16, tile = bt - b * NT16;
    const float* tb = bnd + (size_t)(b * NT16 + tile) * 6;
    float tlo0 = tb[0], thi0 = tb[1], tlo1 = tb[2], thi1 = tb[3], tlo2 = tb[4], thi2 = tb[5];
    unsigned m = 0;
    for (int bit = 0; bit < 32; bit++) {
        int jb = z * 32 + bit;
        const float* a0 = bnd + (size_t)(b * NT16 + 2 * jb) * 6;
        const float* a1 = bnd + (size_t)(b * NT16 + 2 * jb + 1) * 6;
        float s = 0.f;
#pragma unroll
        for (int f = 0; f < 3; f++) {
            float jlo = fminf(a0[2 * f], a1[2 * f]);
            float jhi = fmaxf(a0[2 * f + 1], a1[2 * f + 1]);
            float lo = (f == 0) ? tlo0 : (f == 1) ? tlo1 : tlo2;
            float hi = (f == 0) ? thi0 : (f == 1) ? thi1 : thi2;
            float gap = fmaxf(0.f, fmaxf(lo - jhi, jlo - hi));
            s = fmaf(gap, gap, s);
        }
        if (s <= PRUNE_T) m |= (1u << bit);
    }
    mask[(size_t)bt * ZS + z] = m;
}

// ---------------- K1: per-pixel softmax; writes plane-major bf16 + sorted --
__global__ __launch_bounds__(256) void softmax_kernel(
    const float* __restrict__ q, const int* __restrict__ spos,
    unsigned short* __restrict__ smpb,   // [B*CC][N] bf16 plane-major
    unsigned short* __restrict__ smht,   // [B][32][N] bf16 sorted
    float* __restrict__ part)            // [B][N][24] zeroed here
{
    int idx = blockIdx.x * 256 + threadIdx.x;
    if (idx >= BB * NN) return;
    int b = idx / NN, p = idx - b * NN;
    const float* qp = q + (size_t)idx * CC;
    float v[CC], m = -1e30f;
#pragma unroll
    for (int c = 0; c < CC; c++) { v[c] = qp[c]; m = fmaxf(m, v[c]); }
    float ssum = 0.f;
#pragma unroll
    for (int c = 0; c < CC; c++) { v[c] = __expf(v[c] - m); ssum += v[c]; }
    float inv = 1.0f / ssum;
    int s = spos[idx];
#pragma unroll
    for (int c = 0; c < CC; c++) {
        unsigned short h = bf16_1(v[c] * inv);
        smpb[(size_t)(b * CC + c) * NN + p] = h;
        smht[(size_t)(b * 32 + c) * NN + s] = h;
    }
    float* pp = part + (size_t)(b * NN + s) * 24;
#pragma unroll
    for (int k = 0; k < 24; k++) pp[k] = 0.f;
}

// ---------------- K2a: spatial conv = G @ P @ G via MFMA, one plane/block --
// GEMM1: C1 = P @ G  (A-frags from global bf16 plane, B = G rows, symmetric)
// transpose C1 -> LDS bf16; GEMM2: SP = G @ C1, normalize by S[y]*S[x].
__global__ __launch_bounds__(256) void conv_kernel(
    const unsigned short* __restrict__ smpb, const unsigned short* __restrict__ gbt,
    const float* __restrict__ sxt, float* __restrict__ spf)
{
    __shared__ unsigned short Gb[96 * GST];
    __shared__ unsigned short C1t[96 * GST];
    __shared__ float sS[96];
    int tid = threadIdx.x;
    int lane = tid & 63, w = tid >> 6;
    int quad = lane >> 4, l16 = lane & 15;
    int bc = blockIdx.x;
    // stage G (dword copies) + S
    for (int o = tid; o < 96 * 48; o += 256) {
        int row = o / 48, col2 = o - row * 48;
        ((unsigned*)&Gb[row * GST])[col2] = ((const unsigned*)(gbt + row * 96))[col2];
    }
    if (tid < 96) sS[tid] = sxt[tid];
    __syncthreads();

    const unsigned short* plane = smpb + (size_t)bc * NN;
    // ---- GEMM1: C1[y][x] = sum_xp P[y][xp] G[xp][x] ----
    for (int mt = w; mt < 6; mt += 4) {
        int m0 = mt * 16;
        short8 a[3];
#pragma unroll
        for (int kk = 0; kk < 3; kk++)
            a[kk] = *(const short8*)(plane + (size_t)(m0 + l16) * 96 + kk * 32 + quad * 8);
        f32x4 acc[6];
#pragma unroll
        for (int nt = 0; nt < 6; nt++) acc[nt] = (f32x4){0.f, 0.f, 0.f, 0.f};
#pragma unroll
        for (int nt = 0; nt < 6; nt++) {
#pragma unroll
            for (int kk = 0; kk < 3; kk++) {
                short8 bf = *(const short8*)&Gb[(nt * 16 + l16) * GST + kk * 32 + quad * 8];
                acc[nt] = __builtin_amdgcn_mfma_f32_16x16x32_bf16(a[kk], bf, acc[nt], 0, 0, 0);
            }
        }
        // store transposed bf16: C1t[x][y], x=nt*16+l16, y=m0+quad*4+r
#pragma unroll
        for (int nt = 0; nt < 6; nt++) {
            unsigned* dst = (unsigned*)&C1t[(nt * 16 + l16) * GST + m0 + quad * 4];
            dst[0] = pk_bf16(acc[nt][0], acc[nt][1]);
            dst[1] = pk_bf16(acc[nt][2], acc[nt][3]);
        }
    }
    __syncthreads();
    // ---- GEMM2: SP[y][x] = sum_yp G[y][yp] C1[yp][x], then normalize ----
    float* outp = spf + (size_t)bc * NN;
    for (int mt = w; mt < 6; mt += 4) {
        int m0 = mt * 16;
        short8 a[3];
#pragma unroll
        for (int kk = 0; kk < 3; kk++)
            a[kk] = *(const short8*)&Gb[(m0 + l16) * GST + kk * 32 + quad * 8];
        f32x4 acc[6];
#pragma unroll
        for (int nt = 0; nt < 6; nt++) acc[nt] = (f32x4){0.f, 0.f, 0.f, 0.f};
#pragma unroll
        for (int nt = 0; nt < 6; nt++) {
#pragma unroll
            for (int kk = 0; kk < 3; kk++) {
                short8 bf = *(const short8*)&C1t[(nt * 16 + l16) * GST + kk * 32 + quad * 8];
                acc[nt] = __builtin_amdgcn_mfma_f32_16x16x32_bf16(a[kk], bf, acc[nt], 0, 0, 0);
            }
        }
#pragma unroll
        for (int nt = 0; nt < 6; nt++) {
            int x = nt * 16 + l16;
            float sx = sS[x];
#pragma unroll
            for (int r = 0; r < 4; r++) {
                int y = m0 + quad * 4 + r;
                float invn = __builtin_amdgcn_rcpf(sS[y] * sx);
                outp[y * 96 + x] = acc[nt][r] * invn;
            }
        }
    }
}

// ---------------- K2b: sparse bilateral via skip mask + MFMA ----------------
__global__ __launch_bounds__(256) void bilateral_sparse_kernel(
    const unsigned short* __restrict__ smht, const float* __restrict__ fjs,
    const unsigned* __restrict__ mask, float* __restrict__ part)
{
    int tid = threadIdx.x;
    int lane = tid & 63, w = tid >> 6;
    int quad = lane >> 4, l16 = lane & 15;
    int b = blockIdx.y, z = blockIdx.z;
    int tile16 = blockIdx.x * 4 + w;
    int i = tile16 * 16 + l16;
    const float* fb = fjs + (size_t)b * 5 * NN;
    float fi0 = fb[0 * NN + i], fi1 = fb[1 * NN + i], fi2 = fb[2 * NN + i];
    float fi3 = fb[3 * NN + i], fi4 = fb[4 * NN + i];
    f32x4 acc0 = {0.f, 0.f, 0.f, 0.f};
    f32x4 acc1 = {0.f, 0.f, 0.f, 0.f};
    const unsigned short* smb = smht + (size_t)b * 32 * NN;
    unsigned m = mask[(size_t)(b * NT16 + tile16) * ZS + z];
    while (m) {
        int bit = __ffs(m) - 1;
        m &= m - 1;
        int coff = (z * 32 + bit) * 32 + quad * 8;
        float vf[5][8];
#pragma unroll
        for (int f = 0; f < 5; f++) {
            const float4* pf = (const float4*)(fb + (size_t)f * NN + coff);
            float4 lo = pf[0], hi = pf[1];
            vf[f][0] = lo.x; vf[f][1] = lo.y; vf[f][2] = lo.z; vf[f][3] = lo.w;
            vf[f][4] = hi.x; vf[f][5] = hi.y; vf[f][6] = hi.z; vf[f][7] = hi.w;
        }
        float kf[8];
#pragma unroll
        for (int e = 0; e < 8; e++) {
            float d0 = vf[0][e] - fi0;
            float d1 = vf[1][e] - fi1;
            float d2 = vf[2][e] - fi2;
            float d3 = vf[3][e] - fi3;
            float d4 = vf[4][e] - fi4;
            float s = d0 * d0;
            s = fmaf(d1, d1, s);
            s = fmaf(d2, d2, s);
            s = fmaf(d3, d3, s);
            s = fmaf(d4, d4, s);
            kf[e] = __builtin_amdgcn_exp2f(-s);
        }
        int4v ap = { (int)pk_bf16(kf[0], kf[1]), (int)pk_bf16(kf[2], kf[3]),
                     (int)pk_bf16(kf[4], kf[5]), (int)pk_bf16(kf[6], kf[7]) };
        short8 afrag = __builtin_bit_cast(short8, ap);
        short8 b0 = *(const short8*)(smb + (size_t)l16 * NN + coff);
        short8 b1 = *(const short8*)(smb + (size_t)(16 + l16) * NN + coff);
        acc0 = __builtin_amdgcn_mfma_f32_16x16x32_bf16(afrag, b0, acc0, 0, 0, 0);
        acc1 = __builtin_amdgcn_mfma_f32_16x16x32_bf16(afrag, b1, acc1, 0, 0, 0);
    }
    int ibase = tile16 * 16 + quad * 4;
    float* pr = part + (size_t)b * NN * 24;
#pragma unroll
    for (int r = 0; r < 4; r++)
        atomicAdd(&pr[(size_t)(ibase + r) * 24 + l16], acc0[r]);
    if (l16 < 6) {
#pragma unroll
        for (int r = 0; r < 4; r++)
            atomicAdd(&pr[(size_t)(ibase + r) * 24 + 16 + l16], acc1[r]);
    }
}

// ---------------- K3: per-pixel norm + messages + update -------------------
__global__ __launch_bounds__(256) void update_kernel(
    const float* __restrict__ u, const float* __restrict__ spf,
    const float* __restrict__ part, const int* __restrict__ spos,
    const float* __restrict__ Ws, const float* __restrict__ Wb,
    const float* __restrict__ M, float* __restrict__ qout)
{
    __shared__ float sWs[441], sWb[441], sM[441];
    for (int t = threadIdx.x; t < 441; t += 256) {
        sWs[t] = Ws[t]; sWb[t] = Wb[t]; sM[t] = M[t];
    }
    __syncthreads();
    int idx = blockIdx.x * 256 + threadIdx.x;
    if (idx >= BB * NN) return;
    int b = idx / NN, p = idx - b * NN;
    const float* pp = part + (size_t)(b * NN + spos[idx]) * 24;
    float blv[22];
#pragma unroll
    for (int c = 0; c < 22; c++) blv[c] = pp[c];
    float ninv = 1.0f / blv[21];
    float spv[CC], msg[CC];
#pragma unroll
    for (int c = 0; c < CC; c++) {
        blv[c] *= ninv;
        spv[c] = spf[(size_t)(b * CC + c) * NN + p];
    }
#pragma unroll
    for (int c = 0; c < CC; c++) {
        float a = 0.f;
        const float* wr = &sWs[c * CC];
        const float* br = &sWb[c * CC];
#pragma unroll
        for (int c2 = 0; c2 < CC; c2++) a = fmaf(wr[c2], spv[c2], a);
#pragma unroll
        for (int c2 = 0; c2 < CC; c2++) a = fmaf(br[c2], blv[c2], a);
        msg[c] = a;
    }
    const float* up = u + (size_t)idx * CC;
    float* qp = qout + (size_t)idx * CC;
#pragma unroll
    for (int c = 0; c < CC; c++) {
        float a = up[c];
        const float* mr = &sM[c * CC];
#pragma unroll
        for (int c2 = 0; c2 < CC; c2++) a = fmaf(-mr[c2], msg[c2], a);
        qp[c] = a;
    }
}

extern "C" void kernel_launch(void* const* d_in, const int* in_sizes, int n_in,
                              void* d_out, int out_size, void* d_ws, size_t ws_size,
                              hipStream_t stream)
{
    const float* unary = (const float*)d_in[0];  // [B,H,W,C]
    const float* rgb   = (const float*)d_in[1];  // [B,H,W,3]
    const float* Ws    = (const float*)d_in[2];
    const float* Wb    = (const float*)d_in[3];
    const float* M     = (const float*)d_in[4];
    float* out = (float*)d_out;                  // [B,N,C]

    float* SXT  = (float*)d_ws;                            // 96
    float* FJS  = SXT + 96;                                // B*5*N
    float* SPF  = FJS + (size_t)BB * 5 * NN;               // B*21*N
    float* PART = SPF + (size_t)BB * CC * NN;              // B*N*24
    float* BND  = PART + (size_t)BB * NN * 24;             // B*576*6
    int*   SPOS = (int*)(BND + (size_t)BB * NT16 * 6);     // B*N
    unsigned* MASK = (unsigned*)(SPOS + BB * NN);          // B*576*9
    unsigned short* SMHT = (unsigned short*)(MASK + (size_t)BB * NT16 * ZS);  // B*32*N
    unsigned short* SMPB = SMHT + (size_t)BB * 32 * NN;    // B*21*N
    unsigned short* GBT  = SMPB + (size_t)BB * CC * NN;    // 96*96

    tables_kernel<<<1, 128, 0, stream>>>(SXT, GBT);
    fill_kernel<<<(BB * 11 * NN + 255) / 256, 256, 0, stream>>>(SMHT);
    sort_kernel<<<BB, 256, 0, stream>>>(rgb, SPOS, FJS);
    bounds_kernel<<<(BB * NT16 + 255) / 256, 256, 0, stream>>>(FJS, BND);
    mask_kernel<<<(BB * NT16 * ZS + 255) / 256, 256, 0, stream>>>(BND, MASK);

    for (int it = 0; it < 5; ++it) {
        const float* qsrc = (it == 0) ? unary : out;
        softmax_kernel<<<(BB * NN + 255) / 256, 256, 0, stream>>>(qsrc, SPOS, SMPB, SMHT, PART);
        conv_kernel<<<BB * CC, 256, 0, stream>>>(SMPB, GBT, SXT, SPF);
        bilateral_sparse_kernel<<<dim3(NT16 / 4, BB, ZS), 256, 0, stream>>>(SMHT, FJS, MASK, PART);
        update_kernel<<<(BB * NN + 255) / 256, 256, 0, stream>>>(unary, SPF, PART, SPOS,
                                                                 Ws, Wb, M, out);
    }
}

// Round 5
// 405.357 us; speedup vs baseline: 2.8114x; 1.0735x over previous
//
#include <hip/hip_runtime.h>

#define HH 96
#define WW 96
#define CC 21
#define BB 2
#define NN (HH*WW)          // 9216
#define NT16 (NN/16)        // 576 sorted 16-tiles per batch
#define NJB  (NN/32)        // 288 j-blocks per batch
#define ZS 9                // mask dwords per tile
#define SLOTS 9             // max 32-jblock chunks per tile (288/32)
#define PRUNE_T 24.0f       // exp2-domain skip threshold
#define GST 104             // LDS row stride for 96-wide bf16 rows

// feature pre-scale folds 1/2 and log2(e): k = exp2(-sum(diff^2))
#define KSA2 (0.84932184f / 160.0f)   // bilateral spatial
#define KSB2 (0.84932184f / 3.0f)     // bilateral color
#define GL2  (1.44269504f / 18.0f)    // spatial kernel exp(-d^2/18) in exp2 units

typedef __attribute__((ext_vector_type(4))) float f32x4;
typedef __attribute__((ext_vector_type(8))) short short8;
typedef __attribute__((ext_vector_type(4))) int int4v;

static __device__ inline unsigned pk_bf16(float a, float b) {
    unsigned ua = __builtin_bit_cast(unsigned, a);
    unsigned ub = __builtin_bit_cast(unsigned, b);
    ua += 0x7FFF + ((ua >> 16) & 1);
    ub += 0x7FFF + ((ub >> 16) & 1);
    return (ua >> 16) | (ub & 0xFFFF0000u);
}
static __device__ inline unsigned short bf16_1(float a) {
    unsigned ua = __builtin_bit_cast(unsigned, a);
    ua += 0x7FFF + ((ua >> 16) & 1);
    return (unsigned short)(ua >> 16);
}

// ---------------- P0: Gaussian matrix (bf16) + 1D row-sum table ------------
__global__ __launch_bounds__(128) void tables_kernel(
    float* __restrict__ sxt, unsigned short* __restrict__ gbt)
{
    __shared__ float gt[96];
    int t = threadIdx.x;
    if (t < 96) gt[t] = __builtin_amdgcn_exp2f(-(float)(t * t) * GL2);
    __syncthreads();
    if (t < 96) {
        float s = 0.f;
        for (int v = 0; v < 96; v++) s += gt[abs(t - v)];
        sxt[t] = s;
        for (int v = 0; v < 96; v++) gbt[t * 96 + v] = bf16_1(gt[abs(t - v)]);
    }
}

// ---------------- P0b: constant rows 21..31 of sorted bf16 softmax ---------
__global__ __launch_bounds__(256) void fill_kernel(unsigned short* __restrict__ smht)
{
    int idx = blockIdx.x * 256 + threadIdx.x;
    if (idx >= BB * 11 * NN) return;
    int b = idx / (11 * NN);
    int rem = idx - b * 11 * NN;
    int r = rem / NN, col = rem - r * NN;
    smht[(size_t)(b * 32 + 21 + r) * NN + col] = (r == 0) ? 0x3F80 : 0;
}

// ---------------- P1: parallel counting sort by 12-bit color cell ----------
__global__ __launch_bounds__(256) void zeroh_kernel(int* __restrict__ gh)
{
    int idx = blockIdx.x * 256 + threadIdx.x;
    if (idx < BB * 4096) gh[idx] = 0;
}

__global__ __launch_bounds__(256) void hist_kernel(
    const float* __restrict__ rgb, int* __restrict__ gh)
{
    int idx = blockIdx.x * 256 + threadIdx.x;
    if (idx >= BB * NN) return;
    int b = idx / NN;
    const float* rp = rgb + (size_t)idx * 3;
    int cr = min(15, (int)rp[0] >> 4);
    int cg = min(15, (int)rp[1] >> 4);
    int cb = min(15, (int)rp[2] >> 4);
    atomicAdd(&gh[b * 4096 + ((cr << 8) | (cg << 4) | cb)], 1);
}

__global__ __launch_bounds__(256) void scan_kernel(
    const int* __restrict__ gh, int* __restrict__ goff)
{
    __shared__ int ps[256];
    int t = threadIdx.x;
    for (int b = 0; b < BB; b++) {
        int base = b * 4096 + t * 16;
        int loc[16], s = 0;
#pragma unroll
        for (int k = 0; k < 16; k++) { loc[k] = gh[base + k]; s += loc[k]; }
        ps[t] = s;
        __syncthreads();
        for (int off = 1; off < 256; off <<= 1) {
            int add = (t >= off) ? ps[t - off] : 0;
            __syncthreads();
            ps[t] += add;
            __syncthreads();
        }
        int run = ps[t] - s;
#pragma unroll
        for (int k = 0; k < 16; k++) { goff[base + k] = run; run += loc[k]; }
        __syncthreads();
    }
}

__global__ __launch_bounds__(256) void scatter_kernel(
    const float* __restrict__ rgb, int* __restrict__ goff,
    int* __restrict__ spos, float* __restrict__ fjs)
{
    int idx = blockIdx.x * 256 + threadIdx.x;
    if (idx >= BB * NN) return;
    int b = idx / NN, p = idx - b * NN;
    const float* rp = rgb + (size_t)idx * 3;
    float r = rp[0], g = rp[1], bl = rp[2];
    int cr = min(15, (int)r >> 4);
    int cg = min(15, (int)g >> 4);
    int cb = min(15, (int)bl >> 4);
    int pos = atomicAdd(&goff[b * 4096 + ((cr << 8) | (cg << 4) | cb)], 1);
    spos[idx] = pos;
    int y = p / WW, x = p - y * WW;
    float* fb = fjs + (size_t)b * 5 * NN;
    fb[0 * NN + pos] = r * KSB2;
    fb[1 * NN + pos] = g * KSB2;
    fb[2 * NN + pos] = bl * KSB2;
    fb[3 * NN + pos] = (float)y * KSA2;
    fb[4 * NN + pos] = (float)x * KSA2;
}

// ---------------- P2a: color bbox per sorted 16-tile -----------------------
__global__ __launch_bounds__(256) void bounds_kernel(
    const float* __restrict__ fjs, float* __restrict__ bnd)
{
    int idx = blockIdx.x * 256 + threadIdx.x;
    if (idx >= BB * NT16) return;
    int b = idx / NT16, tile = idx - b * NT16;
    const float* fb = fjs + (size_t)b * 5 * NN + tile * 16;
    float lo[3], hi[3];
#pragma unroll
    for (int f = 0; f < 3; f++) { lo[f] = 1e30f; hi[f] = -1e30f; }
    for (int k = 0; k < 16; k++) {
#pragma unroll
        for (int f = 0; f < 3; f++) {
            float v = fb[f * NN + k];
            lo[f] = fminf(lo[f], v); hi[f] = fmaxf(hi[f], v);
        }
    }
    float* o = bnd + (size_t)idx * 6;
#pragma unroll
    for (int f = 0; f < 3; f++) { o[2 * f] = lo[f]; o[2 * f + 1] = hi[f]; }
}

// ---------------- P2b: 288-bit skip mask per (b, tile16) -------------------
__global__ __launch_bounds__(256) void mask_kernel(
    const float* __restrict__ bnd, unsigned* __restrict__ mask)
{
    int idx = blockIdx.x * 256 + threadIdx.x;
    if (idx >= BB * NT16 * ZS) return;
    int z = idx % ZS;
    int bt = idx / ZS;
    int b = bt / NT16, tile = bt - b * NT16;
    const float* tb = bnd + (size_t)(b * NT16 + tile) * 6;
    float tlo0 = tb[0], thi0 = tb[1], tlo1 = tb[2], thi1 = tb[3], tlo2 = tb[4], thi2 = tb[5];
    unsigned m = 0;
    for (int bit = 0; bit < 32; bit++) {
        int jb = z * 32 + bit;
        const float* a0 = bnd + (size_t)(b * NT16 + 2 * jb) * 6;
        const float* a1 = bnd + (size_t)(b * NT16 + 2 * jb + 1) * 6;
        float s = 0.f;
#pragma unroll
        for (int f = 0; f < 3; f++) {
            float jlo = fminf(a0[2 * f], a1[2 * f]);
            float jhi = fmaxf(a0[2 * f + 1], a1[2 * f + 1]);
            float lo = (f == 0) ? tlo0 : (f == 1) ? tlo1 : tlo2;
            float hi = (f == 0) ? thi0 : (f == 1) ? thi1 : thi2;
            float gap = fmaxf(0.f, fmaxf(lo - jhi, jlo - hi));
            s = fmaf(gap, gap, s);
        }
        if (s <= PRUNE_T) m |= (1u << bit);
    }
    mask[(size_t)bt * ZS + z] = m;
}

// ---------------- P2c: compact per-tile kept-jblock list -------------------
__global__ __launch_bounds__(256) void chunks_kernel(
    const unsigned* __restrict__ mask, unsigned short* __restrict__ jlist,
    int* __restrict__ cnt)
{
    int bt = blockIdx.x * 256 + threadIdx.x;
    if (bt >= BB * NT16) return;
    const unsigned* mp = mask + (size_t)bt * ZS;
    unsigned short* jl = jlist + (size_t)bt * NJB;
    int n = 0;
#pragma unroll
    for (int z = 0; z < ZS; z++) {
        unsigned m = mp[z];
        while (m) {
            int bit = __ffs(m) - 1;
            m &= m - 1;
            jl[n++] = (unsigned short)(z * 32 + bit);
        }
    }
    cnt[bt] = n;
}

// ---------------- K1: per-pixel softmax (iteration 0) ----------------------
__global__ __launch_bounds__(256) void softmax_kernel(
    const float* __restrict__ q, const int* __restrict__ spos,
    unsigned short* __restrict__ smpb, unsigned short* __restrict__ smht,
    float* __restrict__ part)
{
    int idx = blockIdx.x * 256 + threadIdx.x;
    if (idx >= BB * NN) return;
    int b = idx / NN, p = idx - b * NN;
    const float* qp = q + (size_t)idx * CC;
    float v[CC], m = -1e30f;
#pragma unroll
    for (int c = 0; c < CC; c++) { v[c] = qp[c]; m = fmaxf(m, v[c]); }
    float ssum = 0.f;
#pragma unroll
    for (int c = 0; c < CC; c++) { v[c] = __expf(v[c] - m); ssum += v[c]; }
    float inv = 1.0f / ssum;
    int s = spos[idx];
#pragma unroll
    for (int c = 0; c < CC; c++) {
        unsigned short h = bf16_1(v[c] * inv);
        smpb[(size_t)(b * CC + c) * NN + p] = h;
        smht[(size_t)(b * 32 + c) * NN + s] = h;
    }
    float* pp = part + (size_t)(b * NN + s) * 24;
#pragma unroll
    for (int k = 0; k < 24; k++) pp[k] = 0.f;
}

// ---------------- K2a: spatial conv = G @ P @ G via MFMA -------------------
__global__ __launch_bounds__(256) void conv_kernel(
    const unsigned short* __restrict__ smpb, const unsigned short* __restrict__ gbt,
    const float* __restrict__ sxt, float* __restrict__ spf)
{
    __shared__ unsigned short Gb[96 * GST];
    __shared__ unsigned short C1t[96 * GST];
    __shared__ float sS[96];
    int tid = threadIdx.x;
    int lane = tid & 63, w = tid >> 6;
    int quad = lane >> 4, l16 = lane & 15;
    int bc = blockIdx.x;
    for (int o = tid; o < 96 * 48; o += 256) {
        int row = o / 48, col2 = o - row * 48;
        ((unsigned*)&Gb[row * GST])[col2] = ((const unsigned*)(gbt + row * 96))[col2];
    }
    if (tid < 96) sS[tid] = sxt[tid];
    __syncthreads();

    const unsigned short* plane = smpb + (size_t)bc * NN;
    for (int mt = w; mt < 6; mt += 4) {
        int m0 = mt * 16;
        short8 a[3];
#pragma unroll
        for (int kk = 0; kk < 3; kk++)
            a[kk] = *(const short8*)(plane + (size_t)(m0 + l16) * 96 + kk * 32 + quad * 8);
        f32x4 acc[6];
#pragma unroll
        for (int nt = 0; nt < 6; nt++) acc[nt] = (f32x4){0.f, 0.f, 0.f, 0.f};
#pragma unroll
        for (int nt = 0; nt < 6; nt++) {
#pragma unroll
            for (int kk = 0; kk < 3; kk++) {
                short8 bf = *(const short8*)&Gb[(nt * 16 + l16) * GST + kk * 32 + quad * 8];
                acc[nt] = __builtin_amdgcn_mfma_f32_16x16x32_bf16(a[kk], bf, acc[nt], 0, 0, 0);
            }
        }
#pragma unroll
        for (int nt = 0; nt < 6; nt++) {
            unsigned* dst = (unsigned*)&C1t[(nt * 16 + l16) * GST + m0 + quad * 4];
            dst[0] = pk_bf16(acc[nt][0], acc[nt][1]);
            dst[1] = pk_bf16(acc[nt][2], acc[nt][3]);
        }
    }
    __syncthreads();
    float* outp = spf + (size_t)bc * NN;
    for (int mt = w; mt < 6; mt += 4) {
        int m0 = mt * 16;
        short8 a[3];
#pragma unroll
        for (int kk = 0; kk < 3; kk++)
            a[kk] = *(const short8*)&Gb[(m0 + l16) * GST + kk * 32 + quad * 8];
        f32x4 acc[6];
#pragma unroll
        for (int nt = 0; nt < 6; nt++) acc[nt] = (f32x4){0.f, 0.f, 0.f, 0.f};
#pragma unroll
        for (int nt = 0; nt < 6; nt++) {
#pragma unroll
            for (int kk = 0; kk < 3; kk++) {
                short8 bf = *(const short8*)&C1t[(nt * 16 + l16) * GST + kk * 32 + quad * 8];
                acc[nt] = __builtin_amdgcn_mfma_f32_16x16x32_bf16(a[kk], bf, acc[nt], 0, 0, 0);
            }
        }
#pragma unroll
        for (int nt = 0; nt < 6; nt++) {
            int x = nt * 16 + l16;
            float sx = sS[x];
#pragma unroll
            for (int r = 0; r < 4; r++) {
                int y = m0 + quad * 4 + r;
                float invn = __builtin_amdgcn_rcpf(sS[y] * sx);
                outp[y * 96 + x] = acc[nt][r] * invn;
            }
        }
    }
}

// ---------------- K2b: balanced sparse bilateral ---------------------------
// One wave per chunk-slot (tile16, chunk of <=32 kept jblocks). Empty slots
// exit immediately -> uniform work per active wave, no z-split tail.
__global__ __launch_bounds__(256) void bilateral_sparse_kernel(
    const unsigned short* __restrict__ smht, const float* __restrict__ fjs,
    const unsigned short* __restrict__ jlist, const int* __restrict__ cntv,
    float* __restrict__ part)
{
    int tid = threadIdx.x;
    int lane = tid & 63, w = tid >> 6;
    int quad = lane >> 4, l16 = lane & 15;
    int slot = blockIdx.x * 4 + w;            // 0 .. BB*NT16*SLOTS-1
    int bt = slot / SLOTS;
    int ck = slot - bt * SLOTS;
    int cnt = cntv[bt] - ck * 32;
    if (cnt <= 0) return;
    cnt = min(cnt, 32);
    int b = bt / NT16, tile16 = bt - b * NT16;
    int i = tile16 * 16 + l16;
    const float* fb = fjs + (size_t)b * 5 * NN;
    float fi0 = fb[0 * NN + i], fi1 = fb[1 * NN + i], fi2 = fb[2 * NN + i];
    float fi3 = fb[3 * NN + i], fi4 = fb[4 * NN + i];
    f32x4 acc0 = {0.f, 0.f, 0.f, 0.f};
    f32x4 acc1 = {0.f, 0.f, 0.f, 0.f};
    const unsigned short* smb = smht + (size_t)b * 32 * NN;
    const unsigned short* jl = jlist + (size_t)bt * NJB + ck * 32;
    int jb = jl[0];
    for (int k = 0; k < cnt; k++) {
        int jbn = jl[min(k + 1, cnt - 1)];   // prefetch next index
        int coff = jb * 32 + quad * 8;
        float vf[5][8];
#pragma unroll
        for (int f = 0; f < 5; f++) {
            const float4* pf = (const float4*)(fb + (size_t)f * NN + coff);
            float4 lo = pf[0], hi = pf[1];
            vf[f][0] = lo.x; vf[f][1] = lo.y; vf[f][2] = lo.z; vf[f][3] = lo.w;
            vf[f][4] = hi.x; vf[f][5] = hi.y; vf[f][6] = hi.z; vf[f][7] = hi.w;
        }
        float kf[8];
#pragma unroll
        for (int e = 0; e < 8; e++) {
            float d0 = vf[0][e] - fi0;
            float d1 = vf[1][e] - fi1;
            float d2 = vf[2][e] - fi2;
            float d3 = vf[3][e] - fi3;
            float d4 = vf[4][e] - fi4;
            float s = d0 * d0;
            s = fmaf(d1, d1, s);
            s = fmaf(d2, d2, s);
            s = fmaf(d3, d3, s);
            s = fmaf(d4, d4, s);
            kf[e] = __builtin_amdgcn_exp2f(-s);
        }
        int4v ap = { (int)pk_bf16(kf[0], kf[1]), (int)pk_bf16(kf[2], kf[3]),
                     (int)pk_bf16(kf[4], kf[5]), (int)pk_bf16(kf[6], kf[7]) };
        short8 afrag = __builtin_bit_cast(short8, ap);
        short8 b0 = *(const short8*)(smb + (size_t)l16 * NN + coff);
        short8 b1 = *(const short8*)(smb + (size_t)(16 + l16) * NN + coff);
        acc0 = __builtin_amdgcn_mfma_f32_16x16x32_bf16(afrag, b0, acc0, 0, 0, 0);
        acc1 = __builtin_amdgcn_mfma_f32_16x16x32_bf16(afrag, b1, acc1, 0, 0, 0);
        jb = jbn;
    }
    int ibase = tile16 * 16 + quad * 4;
    float* pr = part + (size_t)b * NN * 24;
#pragma unroll
    for (int r = 0; r < 4; r++)
        atomicAdd(&pr[(size_t)(ibase + r) * 24 + l16], acc0[r]);
    if (l16 < 6) {
#pragma unroll
        for (int r = 0; r < 4; r++)
            atomicAdd(&pr[(size_t)(ibase + r) * 24 + 16 + l16], acc1[r]);
    }
}

// ------- K3: norm + messages + update, fused with next iter's softmax ------
__global__ __launch_bounds__(256) void update_fused_kernel(
    const float* __restrict__ u, const float* __restrict__ spf,
    float* __restrict__ part, const int* __restrict__ spos,
    const float* __restrict__ Ws, const float* __restrict__ Wb,
    const float* __restrict__ M, float* __restrict__ qout,
    unsigned short* __restrict__ smpb, unsigned short* __restrict__ smht, int wr)
{
    __shared__ float sWs[441], sWb[441], sM[441];
    for (int t = threadIdx.x; t < 441; t += 256) {
        sWs[t] = Ws[t]; sWb[t] = Wb[t]; sM[t] = M[t];
    }
    __syncthreads();
    int idx = blockIdx.x * 256 + threadIdx.x;
    if (idx >= BB * NN) return;
    int b = idx / NN, p = idx - b * NN;
    int s = spos[idx];
    float* pp = part + (size_t)(b * NN + s) * 24;
    float blv[22];
#pragma unroll
    for (int c = 0; c < 22; c++) blv[c] = pp[c];
    float ninv = 1.0f / blv[21];
    float spv[CC], msg[CC];
#pragma unroll
    for (int c = 0; c < CC; c++) {
        blv[c] *= ninv;
        spv[c] = spf[(size_t)(b * CC + c) * NN + p];
    }
#pragma unroll
    for (int c = 0; c < CC; c++) {
        float a = 0.f;
        const float* wr2 = &sWs[c * CC];
        const float* br = &sWb[c * CC];
#pragma unroll
        for (int c2 = 0; c2 < CC; c2++) a = fmaf(wr2[c2], spv[c2], a);
#pragma unroll
        for (int c2 = 0; c2 < CC; c2++) a = fmaf(br[c2], blv[c2], a);
        msg[c] = a;
    }
    const float* up = u + (size_t)idx * CC;
    float* qp = qout + (size_t)idx * CC;
    float qv[CC];
#pragma unroll
    for (int c = 0; c < CC; c++) {
        float a = up[c];
        const float* mr = &sM[c * CC];
#pragma unroll
        for (int c2 = 0; c2 < CC; c2++) a = fmaf(-mr[c2], msg[c2], a);
        qv[c] = a;
        qp[c] = a;
    }
    if (wr) {
        // fused softmax of the new q for the next iteration
        float m = -1e30f;
#pragma unroll
        for (int c = 0; c < CC; c++) m = fmaxf(m, qv[c]);
        float ssum = 0.f;
#pragma unroll
        for (int c = 0; c < CC; c++) { qv[c] = __expf(qv[c] - m); ssum += qv[c]; }
        float inv = 1.0f / ssum;
#pragma unroll
        for (int c = 0; c < CC; c++) {
            unsigned short h = bf16_1(qv[c] * inv);
            smpb[(size_t)(b * CC + c) * NN + p] = h;
            smht[(size_t)(b * 32 + c) * NN + s] = h;
        }
#pragma unroll
        for (int k = 0; k < 24; k++) pp[k] = 0.f;   // zero PART for next iter
    }
}

extern "C" void kernel_launch(void* const* d_in, const int* in_sizes, int n_in,
                              void* d_out, int out_size, void* d_ws, size_t ws_size,
                              hipStream_t stream)
{
    const float* unary = (const float*)d_in[0];  // [B,H,W,C]
    const float* rgb   = (const float*)d_in[1];  // [B,H,W,3]
    const float* Ws    = (const float*)d_in[2];
    const float* Wb    = (const float*)d_in[3];
    const float* M     = (const float*)d_in[4];
    float* out = (float*)d_out;                  // [B,N,C]

    float* SXT  = (float*)d_ws;                            // 96
    float* FJS  = SXT + 96;                                // B*5*N
    float* SPF  = FJS + (size_t)BB * 5 * NN;               // B*21*N
    float* PART = SPF + (size_t)BB * CC * NN;              // B*N*24
    float* BND  = PART + (size_t)BB * NN * 24;             // B*576*6
    int*   SPOS = (int*)(BND + (size_t)BB * NT16 * 6);     // B*N
    int*   GH   = SPOS + BB * NN;                          // B*4096
    int*   GOFF = GH + BB * 4096;                          // B*4096
    int*   CNT  = GOFF + BB * 4096;                        // B*576
    unsigned* MASK = (unsigned*)(CNT + BB * NT16);         // B*576*9
    unsigned short* JL = (unsigned short*)(MASK + (size_t)BB * NT16 * ZS); // B*576*288
    unsigned short* SMHT = JL + (size_t)BB * NT16 * NJB;   // B*32*N
    unsigned short* SMPB = SMHT + (size_t)BB * 32 * NN;    // B*21*N
    unsigned short* GBT  = SMPB + (size_t)BB * CC * NN;    // 96*96

    tables_kernel<<<1, 128, 0, stream>>>(SXT, GBT);
    fill_kernel<<<(BB * 11 * NN + 255) / 256, 256, 0, stream>>>(SMHT);
    zeroh_kernel<<<(BB * 4096 + 255) / 256, 256, 0, stream>>>(GH);
    hist_kernel<<<(BB * NN + 255) / 256, 256, 0, stream>>>(rgb, GH);
    scan_kernel<<<1, 256, 0, stream>>>(GH, GOFF);
    scatter_kernel<<<(BB * NN + 255) / 256, 256, 0, stream>>>(rgb, GOFF, SPOS, FJS);
    bounds_kernel<<<(BB * NT16 + 255) / 256, 256, 0, stream>>>(FJS, BND);
    mask_kernel<<<(BB * NT16 * ZS + 255) / 256, 256, 0, stream>>>(BND, MASK);
    chunks_kernel<<<(BB * NT16 + 255) / 256, 256, 0, stream>>>(MASK, JL, CNT);

    softmax_kernel<<<(BB * NN + 255) / 256, 256, 0, stream>>>(unary, SPOS, SMPB, SMHT, PART);
    for (int it = 0; it < 5; ++it) {
        conv_kernel<<<BB * CC, 256, 0, stream>>>(SMPB, GBT, SXT, SPF);
        bilateral_sparse_kernel<<<BB * NT16 * SLOTS / 4, 256, 0, stream>>>(
            SMHT, FJS, JL, CNT, PART);
        update_fused_kernel<<<(BB * NN + 255) / 256, 256, 0, stream>>>(
            unary, SPF, PART, SPOS, Ws, Wb, M, out, SMPB, SMHT, (it < 4) ? 1 : 0);
    }
}